// Round 7
// baseline (210.416 us; speedup 1.0000x reference)
//
#include <hip/hip_runtime.h>
#include <hip/hip_bf16.h>
#include <stdint.h>

#define CDIM 512
#define WDIM 2048
#define BDIM 8
#define NGRP 32

typedef unsigned short u16;
typedef __attribute__((ext_vector_type(8))) short bf16x8;
typedef __attribute__((ext_vector_type(4))) float f32x4;

__device__ __forceinline__ float bf2f(u16 u) {
  return __builtin_bit_cast(float, (uint32_t)(u) << 16);
}
__device__ __forceinline__ u16 f2bf(float f) {
  return __builtin_bit_cast(u16, __float2bfloat16(f));
}

__device__ __forceinline__ void gld_lds16(const void* g, void* l) {
  __builtin_amdgcn_global_load_lds(
      (const __attribute__((address_space(1))) uint32_t*)(uintptr_t)(g),
      (__attribute__((address_space(3))) uint32_t*)(uintptr_t)(l),
      16, 0, 0);
}

// ---------------- weight fp32 -> bf16 ----------------
__global__ __launch_bounds__(256) void cvt_weights(
    const float* __restrict__ a, const float* __restrict__ b,
    const float* __restrict__ c, const float* __restrict__ d,
    u16* __restrict__ o) {
  int i = blockIdx.x * 256 + threadIdx.x;  // 262144 elements each
  o[i]          = f2bf(a[i]);
  o[262144 + i] = f2bf(b[i]);
  o[524288 + i] = f2bf(c[i]);
  o[786432 + i] = f2bf(d[i]);
}

// ---------------- groupnorm stats: one block per (b,g) ----------------
__global__ __launch_bounds__(256) void gn_stats(const float* __restrict__ x,
                                                float* __restrict__ mr) {
  const int bg = blockIdx.x;              // b*32+g
  const float4* xp = (const float4*)(x + (size_t)bg * 16 * WDIM);
  const int n4 = 16 * WDIM / 4;           // 8192 float4
  float s = 0.f, s2 = 0.f;
  for (int i = threadIdx.x; i < n4; i += 256) {
    float4 v = xp[i];
    s += v.x + v.y + v.z + v.w;
    s2 = fmaf(v.x, v.x, s2); s2 = fmaf(v.y, v.y, s2);
    s2 = fmaf(v.z, v.z, s2); s2 = fmaf(v.w, v.w, s2);
  }
  for (int off = 32; off; off >>= 1) {
    s  += __shfl_xor(s, off, 64);
    s2 += __shfl_xor(s2, off, 64);
  }
  __shared__ float red[2][4];
  if ((threadIdx.x & 63) == 0) {
    red[0][threadIdx.x >> 6] = s;
    red[1][threadIdx.x >> 6] = s2;
  }
  __syncthreads();
  if (threadIdx.x == 0) {
    float S = red[0][0] + red[0][1] + red[0][2] + red[0][3];
    float S2 = red[1][0] + red[1][1] + red[1][2] + red[1][3];
    const float inv_n = 1.0f / (16.0f * WDIM);
    float m = S * inv_n;
    float var = S2 * inv_n - m * m;
    mr[bg * 2] = m;
    mr[bg * 2 + 1] = rsqrtf(var + 1e-6f);
  }
}

// ---------------- groupnorm apply + transpose -> hT[b][w][c] bf16 ----------------
__global__ __launch_bounds__(256) void gn_apply(
    const float* __restrict__ x, const float* __restrict__ mr,
    const float* __restrict__ gamma, const float* __restrict__ beta,
    u16* __restrict__ hT) {
  const int b = blockIdx.x >> 6;           // 8 batches
  const int w0 = (blockIdx.x & 63) * 32;   // 64 w-tiles of 32
  __shared__ u16 tile[CDIM][33];
  const float* xb = x + (size_t)b * CDIM * WDIM;
  const int c_sub = threadIdx.x >> 5;      // 0..7
  const int w_l = threadIdx.x & 31;
  for (int c0 = 0; c0 < CDIM; c0 += 8) {
    int c = c0 + c_sub;
    int g = c >> 4;
    float m = mr[(b * NGRP + g) * 2];
    float r = mr[(b * NGRP + g) * 2 + 1];
    float v = xb[(size_t)c * WDIM + w0 + w_l];
    float hn = (v - m) * r * gamma[c] + beta[c];
    tile[c][w_l] = f2bf(hn);
  }
  __syncthreads();
  #pragma unroll 4
  for (int i = 0; i < 32; i++) {
    size_t base = ((size_t)b * WDIM + w0 + i) * CDIM;
    hT[base + threadIdx.x] = tile[threadIdx.x][i];
    hT[base + 256 + threadIdx.x] = tile[256 + threadIdx.x][i];
  }
}

// ---------------- deep-pipelined TN GEMM: C[m][n] = sum_k A[m][k]*B[n][k] ----
// BM=256, BN_ in {256,128}, sub-tile BK=32. 512 threads = 8 waves:
//   BN=256: 2(M)x4(N) waves, wave tile 128x64, acc 8x4
//   BN=128: 4(M)x2(N) waves, wave tile  64x64, acc 4x4
// LDS ring-3; stage 2 sub-tiles ahead; steady wait vmcnt(S_CNT), never 0
// mid-loop. READ-AHEAD pipelining: ph1 regs of sub-tile t+1 are ds_read
// right after the end-of-t barrier (left in flight across the loop edge,
// drained by counted lgkmcnt at t+1); ph2 regs are read before ph1's MFMA
// cluster and drained by lgkmcnt(0) after it. 1 barrier per sub-tile.
// LDS layout packs row pairs into 128B super-rows; chunk p within super-row
// S stored at p^(S&7) (same involution on pre-swizzled global source and
// ds_read address; LDS dest linear for global_load_lds) -> conflict-free.
// BIAS_MODE: 0 none, 2 bias[m], 3 split-n (bias at n<512, bias2 at >=512).
template <int BN_, int BIAS_MODE, int RESID, int SCALE, typename OutT>
__global__ __launch_bounds__(512, 2) void gemm_tn(
    const u16* __restrict__ A, const u16* __restrict__ B,
    OutT* __restrict__ Cp, const float* __restrict__ bias,
    const float* __restrict__ bias2, const float* __restrict__ resid,
    float scale, int K, int N, int lda, int ldb,
    long sAb, long sBb, long sCb) {
  constexpr int MI = (BN_ == 256) ? 8 : 4;        // m-frags per wave
  constexpr int WM = MI * 16;                     // wave m-extent
  constexpr int SLOT = 16384 + BN_ * 64;          // bytes: A 16KB + B tile
  constexpr int LDB_CH = BN_ * 4 / 512;           // B loads/thread (2 or 1)
  constexpr int S_CNT = 2 + 1 + (LDB_CH == 2 ? 1 : 0);  // stages/sub-tile
  extern __shared__ char smem[];
  const int tid = threadIdx.x;
  const int wave = tid >> 6, lane = tid & 63;
  const int wr = (BN_ == 256) ? (wave >> 2) : (wave >> 1);
  const int wc = (BN_ == 256) ? (wave & 3) : (wave & 1);
  const int fr = lane & 15, kg = lane >> 4;
  const size_t zc = (size_t)blockIdx.z * sCb;
  const u16* Ab = A + (size_t)blockIdx.z * sAb + (size_t)blockIdx.x * 256 * lda;
  const u16* Bb = B + (size_t)blockIdx.z * sBb + (size_t)blockIdx.y * BN_ * ldb;

  // per-thread staging decode: LDS chunk pc holds global (row, kslot) with
  // S=pc>>3, p=(pc&7)^(S&7), row=2S+(p>>2), kslot=p&3.
  int aoff[2], boff[2];
  #pragma unroll
  for (int j = 0; j < 2; ++j) {
    int pc = j * 512 + tid;
    int S = pc >> 3, p = (pc & 7) ^ (S & 7);
    aoff[j] = (2 * S + (p >> 2)) * lda + (p & 3) * 8;
  }
  #pragma unroll
  for (int j = 0; j < LDB_CH; ++j) {
    int pc = j * 512 + tid;
    int S = pc >> 3, p = (pc & 7) ^ (S & 7);
    boff[j] = (2 * S + (p >> 2)) * ldb + (p & 3) * 8;
  }
  // per-lane ds_read byte base within a tile region
  const int lbase = (fr >> 1) * 128 +
                    (((((fr & 1) << 2) + kg) ^ ((fr >> 1) & 7)) << 4);
  const int sA = wr * WM * 64;            // wave A region byte offset
  const int sB = wc * 64 * 64;            // wave B region byte offset

  f32x4 acc[MI][4] = {};

  auto stageP1 = [&](int buf, int tk) {   // A chunk j0 + B chunk j0
    char* As = smem + buf * SLOT;
    gld_lds16(Ab + aoff[0] + tk * 32, As + tid * 16);
    gld_lds16(Bb + boff[0] + tk * 32, As + 16384 + tid * 16);
  };
  auto stageP2 = [&](int buf, int tk) {   // A chunk j1 (+ B j1 if BN=256)
    char* As = smem + buf * SLOT;
    gld_lds16(Ab + aoff[1] + tk * 32, As + 8192 + tid * 16);
    if constexpr (LDB_CH == 2)
      gld_lds16(Bb + boff[1] + tk * 32, As + 16384 + 8192 + tid * 16);
  };

  const int nt = K >> 5;                  // sub-tiles of 32 (>=16 here)
  stageP1(0, 0); stageP2(0, 0);
  stageP1(1, 1); stageP2(1, 1);
  asm volatile("s_waitcnt vmcnt(%0)" :: "n"(S_CNT) : "memory");
  __builtin_amdgcn_s_barrier();           // all waves' sub-tile 0 resident

  bf16x8 afL[MI / 2], afH[MI / 2], bfv[4];
  // read-ahead: ph1 regs of sub-tile 0
  #pragma unroll
  for (int mi = 0; mi < MI / 2; ++mi)
    afL[mi] = *(const bf16x8*)(smem + sA + mi * 1024 + lbase);
  #pragma unroll
  for (int ni = 0; ni < 4; ++ni)
    bfv[ni] = *(const bf16x8*)(smem + 16384 + sB + ni * 1024 + lbase);

  for (int t = 0; t < nt; ++t) {
    const int buf = t % 3;
    const char* As = smem + buf * SLOT;

    if (t + 2 < nt) stageP1((t + 2) % 3, t + 2);
    // ph2 read-ahead (in flight under ph1's MFMA cluster)
    #pragma unroll
    for (int mi = 0; mi < MI / 2; ++mi)
      afH[mi] = *(const bf16x8*)(As + sA + (MI / 2 + mi) * 1024 + lbase);
    // drain ph1 regs only (the MI/2 ph2 reads just issued may remain)
    asm volatile("s_waitcnt lgkmcnt(%0)" :: "n"(MI / 2) : "memory");
    __builtin_amdgcn_sched_barrier(0);
    __builtin_amdgcn_s_setprio(1);
    #pragma unroll
    for (int mi = 0; mi < MI / 2; ++mi)
      #pragma unroll
      for (int ni = 0; ni < 4; ++ni)
        acc[mi][ni] = __builtin_amdgcn_mfma_f32_16x16x32_bf16(
            afL[mi], bfv[ni], acc[mi][ni], 0, 0, 0);
    __builtin_amdgcn_s_setprio(0);

    if (t + 2 < nt) stageP2((t + 2) % 3, t + 2);
    asm volatile("s_waitcnt lgkmcnt(0)" ::: "memory");
    __builtin_amdgcn_sched_barrier(0);
    __builtin_amdgcn_s_setprio(1);
    #pragma unroll
    for (int mi = 0; mi < MI / 2; ++mi)
      #pragma unroll
      for (int ni = 0; ni < 4; ++ni)
        acc[MI / 2 + mi][ni] = __builtin_amdgcn_mfma_f32_16x16x32_bf16(
            afH[mi], bfv[ni], acc[MI / 2 + mi][ni], 0, 0, 0);
    __builtin_amdgcn_s_setprio(0);

    if (t + 1 < nt) {
      // end-of-sub-tile: tile t+1 fully landed; t+2's stages in flight.
      if (t + 2 < nt)
        asm volatile("s_waitcnt vmcnt(%0)" :: "n"(S_CNT) : "memory");
      else
        asm volatile("s_waitcnt vmcnt(0)" ::: "memory");
      __builtin_amdgcn_s_barrier();
      // read-ahead: ph1 regs of sub-tile t+1 (drained at next lgkmcnt)
      const char* As2 = smem + ((t + 1) % 3) * SLOT;
      const char* Bs2 = As2 + 16384;
      #pragma unroll
      for (int mi = 0; mi < MI / 2; ++mi)
        afL[mi] = *(const bf16x8*)(As2 + sA + mi * 1024 + lbase);
      #pragma unroll
      for (int ni = 0; ni < 4; ++ni)
        bfv[ni] = *(const bf16x8*)(Bs2 + sB + ni * 1024 + lbase);
    }
  }

  const int row0 = blockIdx.x * 256 + wr * WM + kg * 4;
  const int coln = blockIdx.y * BN_ + wc * 64 + fr;
  #pragma unroll
  for (int mi = 0; mi < MI; ++mi) {
    #pragma unroll
    for (int ni = 0; ni < 4; ++ni) {
      int n = coln + ni * 16;
      float badd = 0.0f;
      if (BIAS_MODE == 3) badd = (n < 512) ? bias[n] : bias2[n - 512];
      #pragma unroll
      for (int j = 0; j < 4; ++j) {
        int m = row0 + mi * 16 + j;
        float v = acc[mi][ni][j];
        if (BIAS_MODE == 2) v += bias[m]; else v += badd;
        if (SCALE) v *= scale;
        size_t idx = zc + (size_t)m * N + n;
        if (RESID) v += resid[idx];
        if constexpr (sizeof(OutT) == 2) {
          Cp[idx] = (OutT)f2bf(v);
        } else {
          Cp[idx] = v;
        }
      }
    }
  }
}

// ---------------- row softmax in place over bf16 scores ----------------
__global__ __launch_bounds__(256) void softmax_rows(u16* __restrict__ sc) {
  const size_t base = (size_t)blockIdx.x * WDIM;
  const int tid = threadIdx.x;
  bf16x8 raw = *(const bf16x8*)(sc + base + tid * 8);
  float v[8];
  float mx = -1e30f;
  #pragma unroll
  for (int j = 0; j < 8; j++) {
    v[j] = bf2f((u16)raw[j]);
    mx = fmaxf(mx, v[j]);
  }
  for (int off = 32; off; off >>= 1) mx = fmaxf(mx, __shfl_xor(mx, off, 64));
  __shared__ float smx[4], ssum[4];
  if ((tid & 63) == 0) smx[tid >> 6] = mx;
  __syncthreads();
  mx = fmaxf(fmaxf(smx[0], smx[1]), fmaxf(smx[2], smx[3]));
  float sum = 0.f;
  #pragma unroll
  for (int j = 0; j < 8; j++) {
    v[j] = __expf(v[j] - mx);
    sum += v[j];
  }
  for (int off = 32; off; off >>= 1) sum += __shfl_xor(sum, off, 64);
  if ((tid & 63) == 0) ssum[tid >> 6] = sum;
  __syncthreads();
  float r = 1.0f / (ssum[0] + ssum[1] + ssum[2] + ssum[3]);
  bf16x8 outv;
  #pragma unroll
  for (int j = 0; j < 8; j++) outv[j] = (short)f2bf(v[j] * r);
  *(bf16x8*)(sc + base + tid * 8) = outv;
}

extern "C" void kernel_launch(void* const* d_in, const int* in_sizes, int n_in,
                              void* d_out, int out_size, void* d_ws,
                              size_t ws_size, hipStream_t stream) {
  const float* x     = (const float*)d_in[0];
  const float* gamma = (const float*)d_in[1];
  const float* beta  = (const float*)d_in[2];
  const float* wq    = (const float*)d_in[3];
  const float* bq    = (const float*)d_in[4];
  const float* wk    = (const float*)d_in[5];
  const float* bk    = (const float*)d_in[6];
  const float* wv    = (const float*)d_in[7];
  const float* bv    = (const float*)d_in[8];
  const float* wp    = (const float*)d_in[9];
  const float* bp    = (const float*)d_in[10];
  float* out = (float*)d_out;

  char* ws = (char*)d_ws;
  u16* wq_bf = (u16*)ws;                    // wq,wk contiguous => combined B
  u16* wv_bf = wq_bf + 524288;
  u16* wp_bf = wv_bf + 262144;
  float* mr = (float*)(ws + 4 * 524288);    // 512 floats (mean,rstd)
  u16* hT = (u16*)(ws + 4 * 524288 + 4096); // 8*2048*512
  u16* qk = hT + 8388608;                   // 8*2048*1024 (q | k)
  u16* vB = qk + 16777216;                  // 8*512*2048
  u16* oT = vB + 8388608;                   // 8*2048*512
  u16* sc = oT + 8388608;                   // 8*2048*2048

  const long sWC = (long)WDIM * CDIM;       // 1048576
  const long sCW = (long)CDIM * WDIM;
  const long sW1024 = (long)WDIM * 1024;
  const long sWW = (long)WDIM * WDIM;       // 4194304

  const int SMEM256 = 3 * (16384 + 16384); // 98304
  const int SMEM128 = 3 * (16384 + 8192);  // 73728
  (void)hipFuncSetAttribute((const void*)&gemm_tn<256, 3, 0, 0, u16>,
      hipFuncAttributeMaxDynamicSharedMemorySize, SMEM256);
  (void)hipFuncSetAttribute((const void*)&gemm_tn<256, 0, 0, 1, u16>,
      hipFuncAttributeMaxDynamicSharedMemorySize, SMEM256);
  (void)hipFuncSetAttribute((const void*)&gemm_tn<128, 2, 0, 0, u16>,
      hipFuncAttributeMaxDynamicSharedMemorySize, SMEM128);
  (void)hipFuncSetAttribute((const void*)&gemm_tn<128, 0, 0, 0, u16>,
      hipFuncAttributeMaxDynamicSharedMemorySize, SMEM128);
  (void)hipFuncSetAttribute((const void*)&gemm_tn<128, 2, 1, 0, float>,
      hipFuncAttributeMaxDynamicSharedMemorySize, SMEM128);

  cvt_weights<<<1024, 256, 0, stream>>>(wq, wk, wv, wp, wq_bf);
  gn_stats<<<BDIM * NGRP, 256, 0, stream>>>(x, mr);
  gn_apply<<<BDIM * 64, 256, 0, stream>>>(x, mr, gamma, beta, hT);

  const float scale = 0.04419417382415922f;  // 512^-0.5

  // qk[b][w][0:512]=h.Wq^T+bq ; [512:1024]=h.Wk^T+bk   (256 blocks)
  gemm_tn<256, 3, 0, 0, u16><<<dim3(8, 4, 8), 512, SMEM256, stream>>>(
      hT, wq_bf, qk, bq, bk, nullptr, 1.f, 512, 1024, 512, 512,
      sWC, 0, sW1024);
  // v[b][c][w] = Wv . h + bv                           (256 blocks)
  gemm_tn<128, 2, 0, 0, u16><<<dim3(2, 16, 8), 512, SMEM128, stream>>>(
      wv_bf, hT, vB, bv, nullptr, nullptr, 1.f, 512, 2048, 512, 512,
      0, sWC, sCW);
  // scores[b][i][j] = (q . k) * c^-0.5                 (512 blocks)
  gemm_tn<256, 0, 0, 1, u16><<<dim3(8, 8, 8), 512, SMEM256, stream>>>(
      qk, qk + 512, sc, nullptr, nullptr, nullptr, scale, 512, 2048,
      1024, 1024, sW1024, sW1024, sWW);
  // softmax rows
  softmax_rows<<<BDIM * WDIM, 256, 0, stream>>>(sc);
  // oT[b][i][c] = att . v^T                            (256 blocks)
  gemm_tn<128, 0, 0, 0, u16><<<dim3(8, 4, 8), 512, SMEM128, stream>>>(
      sc, vB, oT, nullptr, nullptr, nullptr, 1.f, 2048, 512, 2048, 2048,
      sWW, sCW, sWC);
  // out[b][c][i] = wp . o + bp + x                     (256 blocks)
  gemm_tn<128, 2, 1, 0, float><<<dim3(2, 16, 8), 512, SMEM128, stream>>>(
      wp_bf, oT, out, bp, nullptr, x, 1.f, 512, 2048, 512, 512,
      0, sWC, sCW);
}

// Round 8
// 207.201 us; speedup vs baseline: 1.0155x; 1.0155x over previous
//
#include <hip/hip_runtime.h>
#include <hip/hip_bf16.h>
#include <stdint.h>

#define CDIM 512
#define WDIM 2048
#define BDIM 8
#define NGRP 32

typedef unsigned short u16;
typedef __attribute__((ext_vector_type(8))) short bf16x8;
typedef __attribute__((ext_vector_type(4))) float f32x4;

__device__ __forceinline__ float bf2f(u16 u) {
  return __builtin_bit_cast(float, (uint32_t)(u) << 16);
}
__device__ __forceinline__ u16 f2bf(float f) {
  return __builtin_bit_cast(u16, __float2bfloat16(f));
}

__device__ __forceinline__ void gld_lds16(const void* g, void* l) {
  __builtin_amdgcn_global_load_lds(
      (const __attribute__((address_space(1))) uint32_t*)(uintptr_t)(g),
      (__attribute__((address_space(3))) uint32_t*)(uintptr_t)(l),
      16, 0, 0);
}

// ---------------- weight fp32 -> bf16 ----------------
__global__ __launch_bounds__(256) void cvt_weights(
    const float* __restrict__ a, const float* __restrict__ b,
    const float* __restrict__ c, const float* __restrict__ d,
    u16* __restrict__ o) {
  int i = blockIdx.x * 256 + threadIdx.x;  // 262144 elements each
  o[i]          = f2bf(a[i]);
  o[262144 + i] = f2bf(b[i]);
  o[524288 + i] = f2bf(c[i]);
  o[786432 + i] = f2bf(d[i]);
}

// ---------------- fused groupnorm: one block per (b,g), x read ONCE --------
// pass1: read 16ch x 2048w fp32, accumulate sum/sumsq, cache bf16 in LDS.
// reduce -> mean/rstd. pass2: affine from LDS, write hT[b][w][c] transposed.
__global__ __launch_bounds__(256) void gn_fused(
    const float* __restrict__ x, const float* __restrict__ gamma,
    const float* __restrict__ beta, u16* __restrict__ hT) {
  extern __shared__ u16 hbuf[];            // [16][2052] padded
  __shared__ float red[2][4];
  __shared__ float mrsh[2];
  const int bg = blockIdx.x;               // b*32+g
  const int b = bg >> 5, g = bg & 31;
  const int tid = threadIdx.x;
  const float4* xp = (const float4*)(x + (size_t)bg * 16 * WDIM);
  float s = 0.f, s2 = 0.f;
  for (int i = tid; i < 16 * WDIM / 4; i += 256) {
    float4 v = xp[i];
    s += v.x + v.y + v.z + v.w;
    s2 = fmaf(v.x, v.x, s2); s2 = fmaf(v.y, v.y, s2);
    s2 = fmaf(v.z, v.z, s2); s2 = fmaf(v.w, v.w, s2);
    int e = i * 4;                          // cc = e>>11, w = e&2047
    int cc = e >> 11, w = e & 2047;
    u16* p = &hbuf[cc * 2052 + w];
    p[0] = f2bf(v.x); p[1] = f2bf(v.y); p[2] = f2bf(v.z); p[3] = f2bf(v.w);
  }
  for (int off = 32; off; off >>= 1) {
    s  += __shfl_xor(s, off, 64);
    s2 += __shfl_xor(s2, off, 64);
  }
  if ((tid & 63) == 0) { red[0][tid >> 6] = s; red[1][tid >> 6] = s2; }
  __syncthreads();
  if (tid == 0) {
    float S = red[0][0] + red[0][1] + red[0][2] + red[0][3];
    float S2 = red[1][0] + red[1][1] + red[1][2] + red[1][3];
    const float inv_n = 1.0f / (16.0f * WDIM);
    float m = S * inv_n;
    float var = S2 * inv_n - m * m;
    mrsh[0] = m; mrsh[1] = rsqrtf(var + 1e-6f);
  }
  __syncthreads();
  const float m = mrsh[0], r = mrsh[1];
  float ga[16], bb[16];
  #pragma unroll
  for (int cc = 0; cc < 16; ++cc) {
    float gm = gamma[g * 16 + cc] * r;
    ga[cc] = gm;
    bb[cc] = beta[g * 16 + cc] - m * gm;
  }
  #pragma unroll
  for (int rr = 0; rr < 8; ++rr) {
    int w = rr * 256 + tid;
    u16 ov[16];
    #pragma unroll
    for (int cc = 0; cc < 16; ++cc)
      ov[cc] = f2bf(fmaf(bf2f(hbuf[cc * 2052 + w]), ga[cc], bb[cc]));
    u16* dst = hT + ((size_t)b * WDIM + w) * CDIM + g * 16;
    *(uint4*)(dst)     = *(const uint4*)(&ov[0]);
    *(uint4*)(dst + 8) = *(const uint4*)(&ov[8]);
  }
}

// ---------------- TN GEMM: C[m][n] = sum_k A[m][k]*B[n][k] ----------------
// BM=128, BN=128, BK=32 sub-tiles. 256 threads = 4 waves (2x2), wave 64x64,
// acc 4x4 (64 VGPR). Ring-2 LDS 32KB -> 3 blocks/CU (the m132 lever: cross-
// block overlap hides the per-sub-tile vmcnt(0) drain + prologue/epilogue).
// Read-ahead: ph1 regs (afL+bfv) of tile t issued right after end-of-(t-1)
// barrier, drained by counted lgkmcnt(2) at t (afH's 2 reads stay out);
// afH drained by lgkmcnt(0) after ph1 MFMA. One barrier per sub-tile.
// Swizzle: chunk slot ^= row&3 on BOTH pre-swizzled global source and
// ds_read address (LDS linear for gld_lds) -> 2 lanes/bank = conflict-free.
// BIAS_MODE: 0 none, 2 bias[m], 3 split-n (bias n<512, bias2 n>=512).
template <int BIAS_MODE, int RESID, int SCALE, typename OutT>
__global__ __launch_bounds__(256, 3) void gemm_tn(
    const u16* __restrict__ A, const u16* __restrict__ B,
    OutT* __restrict__ Cp, const float* __restrict__ bias,
    const float* __restrict__ bias2, const float* __restrict__ resid,
    float scale, int K, int N, int lda, int ldb,
    long sAb, long sBb, long sCb) {
  extern __shared__ char smem[];           // 2 * (8KB A + 8KB B) = 32768
  const int tid = threadIdx.x;
  const int wave = tid >> 6, lane = tid & 63;
  const int wm = wave >> 1, wc = wave & 1;   // 2x2 wave grid, tile 64x64
  const int fr = lane & 15, kg = lane >> 4;
  const size_t zc = (size_t)blockIdx.z * sCb;
  const u16* Ab = A + (size_t)blockIdx.z * sAb + (size_t)blockIdx.x * 128 * lda;
  const u16* Bb = B + (size_t)blockIdx.z * sBb + (size_t)blockIdx.y * 128 * ldb;

  // staging decode: LDS chunk pc holds global (row=pc>>2, slot=(pc&3)^(row&3))
  int aoff[2], boff[2];
  #pragma unroll
  for (int j = 0; j < 2; ++j) {
    int pc = j * 256 + tid;
    int row = pc >> 2, ls = (pc & 3) ^ (row & 3);
    aoff[j] = row * lda + ls * 8;
    boff[j] = row * ldb + ls * 8;
  }
  // per-lane ds_read byte base within a 64-row region (rows of 64B)
  const int lbase = fr * 64 + ((kg ^ (fr & 3)) << 4);
  const int sA = wm * 4096;                // wave A region byte offset
  const int sB = 8192 + wc * 4096;         // wave B region byte offset

  f32x4 acc[4][4] = {};

  auto stage = [&](int buf, int tk) {
    char* bs = smem + buf * 16384;
    gld_lds16(Ab + aoff[0] + tk * 32, bs + tid * 16);
    gld_lds16(Ab + aoff[1] + tk * 32, bs + 4096 + tid * 16);
    gld_lds16(Bb + boff[0] + tk * 32, bs + 8192 + tid * 16);
    gld_lds16(Bb + boff[1] + tk * 32, bs + 12288 + tid * 16);
  };

  const int nt = K >> 5;                   // sub-tiles of 32 (>= 16 here)
  stage(0, 0);
  asm volatile("s_waitcnt vmcnt(0)" ::: "memory");
  __builtin_amdgcn_s_barrier();

  bf16x8 afL[2], afH[2], bfv[4];
  #pragma unroll
  for (int mi = 0; mi < 2; ++mi)
    afL[mi] = *(const bf16x8*)(smem + sA + mi * 1024 + lbase);
  #pragma unroll
  for (int ni = 0; ni < 4; ++ni)
    bfv[ni] = *(const bf16x8*)(smem + sB + ni * 1024 + lbase);

  for (int t = 0; t < nt; ++t) {
    const char* Sb = smem + (t & 1) * 16384;
    if (t + 1 < nt) stage((t + 1) & 1, t + 1);   // overwrites tile t-1's buf
    // ph2 read-ahead (in flight under ph1's MFMA)
    #pragma unroll
    for (int mi = 0; mi < 2; ++mi)
      afH[mi] = *(const bf16x8*)(Sb + sA + (2 + mi) * 1024 + lbase);
    asm volatile("s_waitcnt lgkmcnt(2)" ::: "memory");  // edge 6 landed
    __builtin_amdgcn_sched_barrier(0);
    __builtin_amdgcn_s_setprio(1);
    #pragma unroll
    for (int mi = 0; mi < 2; ++mi)
      #pragma unroll
      for (int ni = 0; ni < 4; ++ni)
        acc[mi][ni] = __builtin_amdgcn_mfma_f32_16x16x32_bf16(
            afL[mi], bfv[ni], acc[mi][ni], 0, 0, 0);
    __builtin_amdgcn_s_setprio(0);

    asm volatile("s_waitcnt lgkmcnt(0)" ::: "memory");
    __builtin_amdgcn_sched_barrier(0);
    __builtin_amdgcn_s_setprio(1);
    #pragma unroll
    for (int mi = 0; mi < 2; ++mi)
      #pragma unroll
      for (int ni = 0; ni < 4; ++ni)
        acc[2 + mi][ni] = __builtin_amdgcn_mfma_f32_16x16x32_bf16(
            afH[mi], bfv[ni], acc[2 + mi][ni], 0, 0, 0);
    __builtin_amdgcn_s_setprio(0);

    if (t + 1 < nt) {
      // own reads drained above; own stage of t+1 landed; barrier =>
      // ALL waves' stages landed and reads of the overwritten buf done.
      asm volatile("s_waitcnt vmcnt(0)" ::: "memory");
      __builtin_amdgcn_s_barrier();
      const char* Sn = smem + ((t + 1) & 1) * 16384;
      #pragma unroll
      for (int mi = 0; mi < 2; ++mi)
        afL[mi] = *(const bf16x8*)(Sn + sA + mi * 1024 + lbase);
      #pragma unroll
      for (int ni = 0; ni < 4; ++ni)
        bfv[ni] = *(const bf16x8*)(Sn + sB + ni * 1024 + lbase);
    }
  }

  const int row0 = blockIdx.x * 128 + wm * 64 + kg * 4;
  const int coln = blockIdx.y * 128 + wc * 64 + fr;
  #pragma unroll
  for (int mi = 0; mi < 4; ++mi) {
    #pragma unroll
    for (int ni = 0; ni < 4; ++ni) {
      int n = coln + ni * 16;
      float badd = 0.0f;
      if (BIAS_MODE == 3) badd = (n < 512) ? bias[n] : bias2[n - 512];
      #pragma unroll
      for (int j = 0; j < 4; ++j) {
        int m = row0 + mi * 16 + j;
        float v = acc[mi][ni][j];
        if (BIAS_MODE == 2) v += bias[m]; else v += badd;
        if (SCALE) v *= scale;
        size_t idx = zc + (size_t)m * N + n;
        if (RESID) v += resid[idx];
        if constexpr (sizeof(OutT) == 2) {
          Cp[idx] = (OutT)f2bf(v);
        } else {
          Cp[idx] = v;
        }
      }
    }
  }
}

// ---------------- row softmax in place over bf16 scores ----------------
__global__ __launch_bounds__(256) void softmax_rows(u16* __restrict__ sc) {
  const size_t base = (size_t)blockIdx.x * WDIM;
  const int tid = threadIdx.x;
  bf16x8 raw = *(const bf16x8*)(sc + base + tid * 8);
  float v[8];
  float mx = -1e30f;
  #pragma unroll
  for (int j = 0; j < 8; j++) {
    v[j] = bf2f((u16)raw[j]);
    mx = fmaxf(mx, v[j]);
  }
  for (int off = 32; off; off >>= 1) mx = fmaxf(mx, __shfl_xor(mx, off, 64));
  __shared__ float smx[4], ssum[4];
  if ((tid & 63) == 0) smx[tid >> 6] = mx;
  __syncthreads();
  mx = fmaxf(fmaxf(smx[0], smx[1]), fmaxf(smx[2], smx[3]));
  float sum = 0.f;
  #pragma unroll
  for (int j = 0; j < 8; j++) {
    v[j] = __expf(v[j] - mx);
    sum += v[j];
  }
  for (int off = 32; off; off >>= 1) sum += __shfl_xor(sum, off, 64);
  if ((tid & 63) == 0) ssum[tid >> 6] = sum;
  __syncthreads();
  float r = 1.0f / (ssum[0] + ssum[1] + ssum[2] + ssum[3]);
  bf16x8 outv;
  #pragma unroll
  for (int j = 0; j < 8; j++) outv[j] = (short)f2bf(v[j] * r);
  *(bf16x8*)(sc + base + tid * 8) = outv;
}

extern "C" void kernel_launch(void* const* d_in, const int* in_sizes, int n_in,
                              void* d_out, int out_size, void* d_ws,
                              size_t ws_size, hipStream_t stream) {
  const float* x     = (const float*)d_in[0];
  const float* gamma = (const float*)d_in[1];
  const float* beta  = (const float*)d_in[2];
  const float* wq    = (const float*)d_in[3];
  const float* bq    = (const float*)d_in[4];
  const float* wk    = (const float*)d_in[5];
  const float* bk    = (const float*)d_in[6];
  const float* wv    = (const float*)d_in[7];
  const float* bv    = (const float*)d_in[8];
  const float* wp    = (const float*)d_in[9];
  const float* bp    = (const float*)d_in[10];
  float* out = (float*)d_out;

  char* ws = (char*)d_ws;
  u16* wq_bf = (u16*)ws;                    // wq,wk contiguous => combined B
  u16* wv_bf = wq_bf + 524288;
  u16* wp_bf = wv_bf + 262144;
  u16* hT = (u16*)(ws + 4 * 524288);        // 8*2048*512
  u16* qk = hT + 8388608;                   // 8*2048*1024 (q | k)
  u16* vB = qk + 16777216;                  // 8*512*2048
  u16* oT = vB + 8388608;                   // 8*2048*512
  u16* sc = oT + 8388608;                   // 8*2048*2048

  const long sWC = (long)WDIM * CDIM;       // 1048576
  const long sCW = (long)CDIM * WDIM;
  const long sW1024 = (long)WDIM * 1024;
  const long sWW = (long)WDIM * WDIM;       // 4194304

  const int SMEM = 32768;
  const int GN_SMEM = 16 * 2052 * 2;        // 65664
  (void)hipFuncSetAttribute((const void*)&gn_fused,
      hipFuncAttributeMaxDynamicSharedMemorySize, GN_SMEM);
  (void)hipFuncSetAttribute((const void*)&gemm_tn<3, 0, 0, u16>,
      hipFuncAttributeMaxDynamicSharedMemorySize, SMEM);
  (void)hipFuncSetAttribute((const void*)&gemm_tn<2, 0, 0, u16>,
      hipFuncAttributeMaxDynamicSharedMemorySize, SMEM);
  (void)hipFuncSetAttribute((const void*)&gemm_tn<0, 0, 1, u16>,
      hipFuncAttributeMaxDynamicSharedMemorySize, SMEM);
  (void)hipFuncSetAttribute((const void*)&gemm_tn<0, 0, 0, u16>,
      hipFuncAttributeMaxDynamicSharedMemorySize, SMEM);
  (void)hipFuncSetAttribute((const void*)&gemm_tn<2, 1, 0, float>,
      hipFuncAttributeMaxDynamicSharedMemorySize, SMEM);

  cvt_weights<<<1024, 256, 0, stream>>>(wq, wk, wv, wp, wq_bf);
  gn_fused<<<BDIM * NGRP, 256, GN_SMEM, stream>>>(x, gamma, beta, hT);

  const float scale = 0.04419417382415922f;  // 512^-0.5

  // qk[b][w][0:512]=h.Wq^T+bq ; [512:1024]=h.Wk^T+bk   (1024 blocks)
  gemm_tn<3, 0, 0, u16><<<dim3(16, 8, 8), 256, SMEM, stream>>>(
      hT, wq_bf, qk, bq, bk, nullptr, 1.f, 512, 1024, 512, 512,
      sWC, 0, sW1024);
  // v[b][c][w] = Wv . h + bv                           (512 blocks)
  gemm_tn<2, 0, 0, u16><<<dim3(4, 16, 8), 256, SMEM, stream>>>(
      wv_bf, hT, vB, bv, nullptr, nullptr, 1.f, 512, 2048, 512, 512,
      0, sWC, sCW);
  // scores[b][i][j] = (q . k) * c^-0.5                 (2048 blocks)
  gemm_tn<0, 0, 1, u16><<<dim3(16, 16, 8), 256, SMEM, stream>>>(
      qk, qk + 512, sc, nullptr, nullptr, nullptr, scale, 512, 2048,
      1024, 1024, sW1024, sW1024, sWW);
  // softmax rows
  softmax_rows<<<BDIM * WDIM, 256, 0, stream>>>(sc);
  // oT[b][i][c] = att . v^T                            (512 blocks)
  gemm_tn<0, 0, 0, u16><<<dim3(16, 4, 8), 256, SMEM, stream>>>(
      sc, vB, oT, nullptr, nullptr, nullptr, 1.f, 2048, 512, 2048, 2048,
      sWW, sCW, sWC);
  // out[b][c][i] = wp . o + bp + x                     (512 blocks)
  gemm_tn<2, 1, 0, float><<<dim3(4, 16, 8), 256, SMEM, stream>>>(
      wp_bf, oT, out, bp, nullptr, x, 1.f, 512, 2048, 512, 512,
      0, sWC, sCW);
}

// Round 9
// 206.777 us; speedup vs baseline: 1.0176x; 1.0020x over previous
//
#include <hip/hip_runtime.h>
#include <hip/hip_bf16.h>
#include <stdint.h>

#define CDIM 512
#define WDIM 2048
#define BDIM 8
#define NGRP 32

typedef unsigned short u16;
typedef __attribute__((ext_vector_type(8))) short bf16x8;
typedef __attribute__((ext_vector_type(4))) float f32x4;

__device__ __forceinline__ float bf2f(u16 u) {
  return __builtin_bit_cast(float, (uint32_t)(u) << 16);
}
__device__ __forceinline__ u16 f2bf(float f) {
  return __builtin_bit_cast(u16, __float2bfloat16(f));
}

__device__ __forceinline__ void gld_lds16(const void* g, void* l) {
  __builtin_amdgcn_global_load_lds(
      (const __attribute__((address_space(1))) uint32_t*)(uintptr_t)(g),
      (__attribute__((address_space(3))) uint32_t*)(uintptr_t)(l),
      16, 0, 0);
}

// ---------------- weight fp32 -> bf16 ----------------
__global__ __launch_bounds__(256) void cvt_weights(
    const float* __restrict__ a, const float* __restrict__ b,
    const float* __restrict__ c, const float* __restrict__ d,
    u16* __restrict__ o) {
  int i = blockIdx.x * 256 + threadIdx.x;  // 262144 elements each
  o[i]          = f2bf(a[i]);
  o[262144 + i] = f2bf(b[i]);
  o[524288 + i] = f2bf(c[i]);
  o[786432 + i] = f2bf(d[i]);
}

// ---------------- fused groupnorm: one block per (b,g), x read ONCE --------
__global__ __launch_bounds__(256) void gn_fused(
    const float* __restrict__ x, const float* __restrict__ gamma,
    const float* __restrict__ beta, u16* __restrict__ hT) {
  extern __shared__ u16 hbuf[];            // [16][2052] padded
  __shared__ float red[2][4];
  __shared__ float mrsh[2];
  const int bg = blockIdx.x;               // b*32+g
  const int b = bg >> 5, g = bg & 31;
  const int tid = threadIdx.x;
  const float4* xp = (const float4*)(x + (size_t)bg * 16 * WDIM);
  float s = 0.f, s2 = 0.f;
  for (int i = tid; i < 16 * WDIM / 4; i += 256) {
    float4 v = xp[i];
    s += v.x + v.y + v.z + v.w;
    s2 = fmaf(v.x, v.x, s2); s2 = fmaf(v.y, v.y, s2);
    s2 = fmaf(v.z, v.z, s2); s2 = fmaf(v.w, v.w, s2);
    int e = i * 4;
    int cc = e >> 11, w = e & 2047;
    u16* p = &hbuf[cc * 2052 + w];
    p[0] = f2bf(v.x); p[1] = f2bf(v.y); p[2] = f2bf(v.z); p[3] = f2bf(v.w);
  }
  for (int off = 32; off; off >>= 1) {
    s  += __shfl_xor(s, off, 64);
    s2 += __shfl_xor(s2, off, 64);
  }
  if ((tid & 63) == 0) { red[0][tid >> 6] = s; red[1][tid >> 6] = s2; }
  __syncthreads();
  if (tid == 0) {
    float S = red[0][0] + red[0][1] + red[0][2] + red[0][3];
    float S2 = red[1][0] + red[1][1] + red[1][2] + red[1][3];
    const float inv_n = 1.0f / (16.0f * WDIM);
    float m = S * inv_n;
    float var = S2 * inv_n - m * m;
    mrsh[0] = m; mrsh[1] = rsqrtf(var + 1e-6f);
  }
  __syncthreads();
  const float m = mrsh[0], r = mrsh[1];
  float ga[16], bb[16];
  #pragma unroll
  for (int cc = 0; cc < 16; ++cc) {
    float gm = gamma[g * 16 + cc] * r;
    ga[cc] = gm;
    bb[cc] = beta[g * 16 + cc] - m * gm;
  }
  #pragma unroll
  for (int rr = 0; rr < 8; ++rr) {
    int w = rr * 256 + tid;
    u16 ov[16];
    #pragma unroll
    for (int cc = 0; cc < 16; ++cc)
      ov[cc] = f2bf(fmaf(bf2f(hbuf[cc * 2052 + w]), ga[cc], bb[cc]));
    u16* dst = hT + ((size_t)b * WDIM + w) * CDIM + g * 16;
    *(uint4*)(dst)     = *(const uint4*)(&ov[0]);
    *(uint4*)(dst + 8) = *(const uint4*)(&ov[8]);
  }
}

// ---------------- 8-wave phase-interleaved TN GEMM ----------------
// C[m][n] = sum_k A[m][k]*B[n][k].  BK=32 K-tiles, ring-3 LDS buffers,
// stage 2 tiles ahead.  Configs:
//   (256,256): waves 2x4, wave tile 128x64, 2 phases/tile, 4 loads/tile
//   (256,128): waves 4x2, wave tile  64x64, 1 phase/tile, 3 loads/tile
//   (128,256): waves 2x4, wave tile  64x64, 1 phase/tile, 3 loads/tile
// Per phase: {stage slice | ds_read frags | s_barrier | lgkmcnt(0) |
//            setprio(1) 16 MFMA setprio(0) | [vmcnt(L) at tile end] |
//            s_barrier}.  vmcnt(L) waits only for the tile staged 2 tiles
// ago (counted, never 0 mid-loop).  LDS: row pairs packed in 128B super-
// rows, 16B chunk p at p^(S&7); same involution on pre-swizzled global
// source and ds_read address; LDS dest linear for global_load_lds ->
// uniform 8 touches/bank on ds_read_b128 (conflict-free; R6-verified).
// Race safety: buf (t+2)%3's readers (tile t-1) drained ds_reads via
// lgkmcnt(0) before tile t-1's closing barrier; stages issue after it.
// BIAS_MODE: 0 none, 2 bias[m], 3 split-n (bias n<512, bias2 n>=512).
template <int BM_, int BN_, int BIAS_MODE, int RESID, int SCALE, typename OutT>
__global__ __launch_bounds__(512, 1) void gemm_tn(
    const u16* __restrict__ A, const u16* __restrict__ B,
    OutT* __restrict__ Cp, const float* __restrict__ bias,
    const float* __restrict__ bias2, const float* __restrict__ resid,
    float scale, int K, int N, int lda, int ldb,
    long sAb, long sBb, long sCb) {
  constexpr int WC = (BM_ == 256 && BN_ == 128) ? 2 : 4;
  constexpr int WR = 8 / WC;
  constexpr int WMT = BM_ / WR;            // 128 or 64
  constexpr int MI = WMT / 16;             // 8 or 4
  constexpr int P = MI / 4;                // phases per K-tile: 2 or 1
  constexpr int CA = BM_ / 128;            // A gld_lds per thread per tile
  constexpr int CB = BN_ / 128;
  constexpr int L = CA + CB;               // loads per tile (4 or 3)
  constexpr int ABYTES = BM_ * 64;
  constexpr int SLOT = (BM_ + BN_) * 64;
  extern __shared__ char smem[];
  const int tid = threadIdx.x;
  const int wave = tid >> 6, lane = tid & 63;
  const int wr = wave / WC, wc = wave % WC;
  const int fr = lane & 15, kg = lane >> 4;
  const size_t zc = (size_t)blockIdx.z * sCb;
  const u16* Ab = A + (size_t)blockIdx.z * sAb + (size_t)blockIdx.x * BM_ * lda;
  const u16* Bb = B + (size_t)blockIdx.z * sBb + (size_t)blockIdx.y * BN_ * ldb;

  // staging decode: LDS 16B chunk pc -> super-row S=pc>>3, slot p=(pc&7)^(S&7),
  // global row = 2S+(p>>2), k-chunk = p&3.
  int aoff[CA], boff[CB];
  #pragma unroll
  for (int j = 0; j < CA; ++j) {
    int pc = j * 512 + tid;
    int S = pc >> 3, p = (pc & 7) ^ (S & 7);
    aoff[j] = (2 * S + (p >> 2)) * lda + (p & 3) * 8;
  }
  #pragma unroll
  for (int j = 0; j < CB; ++j) {
    int pc = j * 512 + tid;
    int S = pc >> 3, p = (pc & 7) ^ (S & 7);
    boff[j] = (2 * S + (p >> 2)) * ldb + (p & 3) * 8;
  }
  // per-lane ds_read byte base within an A/B region
  const int rbase = (fr >> 1) * 128 + (((((fr & 1) << 2) | kg) ^ (fr >> 1)) << 4);
  const int sAo = wr * WMT * 64;
  const int sBo = wc * 64 * 64;

  f32x4 acc[MI][4] = {};

  auto stageA = [&](int buf, int tk) {
    char* d = smem + buf * SLOT;
    #pragma unroll
    for (int j = 0; j < CA; ++j)
      gld_lds16(Ab + aoff[j] + tk * 32, d + (j * 512 + tid) * 16);
  };
  auto stageB = [&](int buf, int tk) {
    char* d = smem + buf * SLOT + ABYTES;
    #pragma unroll
    for (int j = 0; j < CB; ++j)
      gld_lds16(Bb + boff[j] + tk * 32, d + (j * 512 + tid) * 16);
  };

  const int nt = K >> 5;                   // >= 16 for all our shapes
  stageA(0, 0); stageB(0, 0);
  stageA(1, 1); stageB(1, 1);
  asm volatile("s_waitcnt vmcnt(%0)" :: "n"(L) : "memory");  // tile 0 landed
  __builtin_amdgcn_s_barrier();

  for (int t = 0; t < nt; ++t) {
    const char* base = smem + (t % 3) * SLOT;
    const bool st = (t + 2 < nt);
    const int sb = (t + 2) % 3;
    bf16x8 af[4], bfv[4];
    #pragma unroll
    for (int ph = 0; ph < P; ++ph) {
      // stage slice of tile t+2
      if (st) {
        if (P == 1) { stageA(sb, t + 2); stageB(sb, t + 2); }
        else if (ph == 0) stageA(sb, t + 2);
        else stageB(sb, t + 2);
      }
      // ds_read this phase's fragments
      #pragma unroll
      for (int i = 0; i < 4; ++i)
        af[i] = *(const bf16x8*)(base + sAo + (ph * 4 + i) * 1024 + rbase);
      if (ph == 0) {
        #pragma unroll
        for (int ni = 0; ni < 4; ++ni)
          bfv[ni] = *(const bf16x8*)(base + ABYTES + sBo + ni * 1024 + rbase);
      }
      __builtin_amdgcn_s_barrier();                    // phase alignment
      asm volatile("s_waitcnt lgkmcnt(0)" ::: "memory");
      __builtin_amdgcn_sched_barrier(0);
      __builtin_amdgcn_s_setprio(1);
      #pragma unroll
      for (int i = 0; i < 4; ++i)
        #pragma unroll
        for (int ni = 0; ni < 4; ++ni)
          acc[ph * 4 + i][ni] = __builtin_amdgcn_mfma_f32_16x16x32_bf16(
              af[i], bfv[ni], acc[ph * 4 + i][ni], 0, 0, 0);
      __builtin_amdgcn_s_setprio(0);
      if (ph == P - 1) {
        if (st)
          asm volatile("s_waitcnt vmcnt(%0)" :: "n"(L) : "memory");
        else if (t + 1 < nt)
          asm volatile("s_waitcnt vmcnt(0)" ::: "memory");
      }
      if (ph < P - 1 || t + 1 < nt)
        __builtin_amdgcn_s_barrier();                  // phase close
    }
  }

  const int row0 = blockIdx.x * BM_ + wr * WMT + kg * 4;
  const int coln = blockIdx.y * BN_ + wc * 64 + fr;
  #pragma unroll
  for (int mi = 0; mi < MI; ++mi) {
    #pragma unroll
    for (int ni = 0; ni < 4; ++ni) {
      int n = coln + ni * 16;
      float badd = 0.0f;
      if (BIAS_MODE == 3) badd = (n < 512) ? bias[n] : bias2[n - 512];
      #pragma unroll
      for (int j = 0; j < 4; ++j) {
        int m = row0 + mi * 16 + j;
        float v = acc[mi][ni][j];
        if (BIAS_MODE == 2) v += bias[m]; else v += badd;
        if (SCALE) v *= scale;
        size_t idx = zc + (size_t)m * N + n;
        if (RESID) v += resid[idx];
        if constexpr (sizeof(OutT) == 2) {
          Cp[idx] = (OutT)f2bf(v);
        } else {
          Cp[idx] = v;
        }
      }
    }
  }
}

// ---------------- row softmax in place over bf16 scores ----------------
__global__ __launch_bounds__(256) void softmax_rows(u16* __restrict__ sc) {
  const size_t base = (size_t)blockIdx.x * WDIM;
  const int tid = threadIdx.x;
  bf16x8 raw = *(const bf16x8*)(sc + base + tid * 8);
  float v[8];
  float mx = -1e30f;
  #pragma unroll
  for (int j = 0; j < 8; j++) {
    v[j] = bf2f((u16)raw[j]);
    mx = fmaxf(mx, v[j]);
  }
  for (int off = 32; off; off >>= 1) mx = fmaxf(mx, __shfl_xor(mx, off, 64));
  __shared__ float smx[4], ssum[4];
  if ((tid & 63) == 0) smx[tid >> 6] = mx;
  __syncthreads();
  mx = fmaxf(fmaxf(smx[0], smx[1]), fmaxf(smx[2], smx[3]));
  float sum = 0.f;
  #pragma unroll
  for (int j = 0; j < 8; j++) {
    v[j] = __expf(v[j] - mx);
    sum += v[j];
  }
  for (int off = 32; off; off >>= 1) sum += __shfl_xor(sum, off, 64);
  if ((tid & 63) == 0) ssum[tid >> 6] = sum;
  __syncthreads();
  float r = 1.0f / (ssum[0] + ssum[1] + ssum[2] + ssum[3]);
  bf16x8 outv;
  #pragma unroll
  for (int j = 0; j < 8; j++) outv[j] = (short)f2bf(v[j] * r);
  *(bf16x8*)(sc + base + tid * 8) = outv;
}

extern "C" void kernel_launch(void* const* d_in, const int* in_sizes, int n_in,
                              void* d_out, int out_size, void* d_ws,
                              size_t ws_size, hipStream_t stream) {
  const float* x     = (const float*)d_in[0];
  const float* gamma = (const float*)d_in[1];
  const float* beta  = (const float*)d_in[2];
  const float* wq    = (const float*)d_in[3];
  const float* bq    = (const float*)d_in[4];
  const float* wk    = (const float*)d_in[5];
  const float* bk    = (const float*)d_in[6];
  const float* wv    = (const float*)d_in[7];
  const float* bv    = (const float*)d_in[8];
  const float* wp    = (const float*)d_in[9];
  const float* bp    = (const float*)d_in[10];
  float* out = (float*)d_out;

  char* ws = (char*)d_ws;
  u16* wq_bf = (u16*)ws;                    // wq,wk contiguous => combined B
  u16* wv_bf = wq_bf + 524288;
  u16* wp_bf = wv_bf + 262144;
  u16* hT = (u16*)(ws + 4 * 524288);        // 8*2048*512
  u16* qk = hT + 8388608;                   // 8*2048*1024 (q | k)
  u16* vB = qk + 16777216;                  // 8*512*2048
  u16* oT = vB + 8388608;                   // 8*2048*512
  u16* sc = oT + 8388608;                   // 8*2048*2048

  const long sWC = (long)WDIM * CDIM;       // 1048576
  const long sCW = (long)CDIM * WDIM;
  const long sW1024 = (long)WDIM * 1024;
  const long sWW = (long)WDIM * WDIM;       // 4194304

  const int SMEM_A = 3 * (256 + 256) * 64;  // 98304
  const int SMEM_B = 3 * (128 + 256) * 64;  // 73728
  const int GN_SMEM = 16 * 2052 * 2;        // 65664
  (void)hipFuncSetAttribute((const void*)&gn_fused,
      hipFuncAttributeMaxDynamicSharedMemorySize, GN_SMEM);
  (void)hipFuncSetAttribute((const void*)&gemm_tn<256, 256, 3, 0, 0, u16>,
      hipFuncAttributeMaxDynamicSharedMemorySize, SMEM_A);
  (void)hipFuncSetAttribute((const void*)&gemm_tn<256, 256, 0, 0, 1, u16>,
      hipFuncAttributeMaxDynamicSharedMemorySize, SMEM_A);
  (void)hipFuncSetAttribute((const void*)&gemm_tn<128, 256, 2, 0, 0, u16>,
      hipFuncAttributeMaxDynamicSharedMemorySize, SMEM_B);
  (void)hipFuncSetAttribute((const void*)&gemm_tn<256, 128, 0, 0, 0, u16>,
      hipFuncAttributeMaxDynamicSharedMemorySize, SMEM_B);
  (void)hipFuncSetAttribute((const void*)&gemm_tn<128, 256, 2, 1, 0, float>,
      hipFuncAttributeMaxDynamicSharedMemorySize, SMEM_B);

  cvt_weights<<<1024, 256, 0, stream>>>(wq, wk, wv, wp, wq_bf);
  gn_fused<<<BDIM * NGRP, 256, GN_SMEM, stream>>>(x, gamma, beta, hT);

  const float scale = 0.04419417382415922f;  // 512^-0.5

  // qk[b][w][0:512]=h.Wq^T+bq ; [512:1024]=h.Wk^T+bk   (256 blocks)
  gemm_tn<256, 256, 3, 0, 0, u16><<<dim3(8, 4, 8), 512, SMEM_A, stream>>>(
      hT, wq_bf, qk, bq, bk, nullptr, 1.f, 512, 1024, 512, 512,
      sWC, 0, sW1024);
  // v[b][c][w] = Wv . h + bv                           (256 blocks)
  gemm_tn<128, 256, 2, 0, 0, u16><<<dim3(4, 8, 8), 512, SMEM_B, stream>>>(
      wv_bf, hT, vB, bv, nullptr, nullptr, 1.f, 512, 2048, 512, 512,
      0, sWC, sCW);
  // scores[b][i][j] = (q . k) * c^-0.5                 (512 blocks)
  gemm_tn<256, 256, 0, 0, 1, u16><<<dim3(8, 8, 8), 512, SMEM_A, stream>>>(
      qk, qk + 512, sc, nullptr, nullptr, nullptr, scale, 512, 2048,
      1024, 1024, sW1024, sW1024, sWW);
  // softmax rows
  softmax_rows<<<BDIM * WDIM, 256, 0, stream>>>(sc);
  // oT[b][i][c] = att . v^T                            (256 blocks)
  gemm_tn<256, 128, 0, 0, 0, u16><<<dim3(8, 4, 8), 512, SMEM_B, stream>>>(
      sc, vB, oT, nullptr, nullptr, nullptr, 1.f, 2048, 512, 2048, 2048,
      sWW, sCW, sWC);
  // out[b][c][i] = wp . o + bp + x                     (256 blocks)
  gemm_tn<128, 256, 2, 1, 0, float><<<dim3(4, 8, 8), 512, SMEM_B, stream>>>(
      wp_bf, oT, out, bp, nullptr, x, 1.f, 512, 2048, 512, 512,
      0, sWC, sCW);
}